// Round 7
// baseline (233.342 us; speedup 1.0000x reference)
//
#include <hip/hip_runtime.h>
#include <hip/hip_bf16.h>
#include <stdint.h>

// SelfAttention: B=4, C=64, H=W=64 -> N=4096 tokens, d=64.
// R6 lesson: occupancy 11->43% gave ZERO speedup (128us) -> per-tile serial chain is
// dominated by exposed global-load latency (K wait + V wait per tile), which queues
// under load. R7: register prefetch (V issued at tile start, K[t+1] issued after
// QK^T) so both waits hide under softmax; s_setprio around MFMA; nsplit=4.

#define DIM  64
#define NTOK 4096
#define NB   4

typedef float  f32x4 __attribute__((ext_vector_type(4)));
typedef float  f32x2 __attribute__((ext_vector_type(2)));
typedef __bf16 bf16x8 __attribute__((ext_vector_type(8)));
typedef _Float16 f16x8 __attribute__((ext_vector_type(8)));
typedef unsigned short u16x8 __attribute__((ext_vector_type(8)));
typedef unsigned short u16x4 __attribute__((ext_vector_type(4)));

__device__ __forceinline__ unsigned short f2h(float f) {
  return __builtin_bit_cast(unsigned short, (_Float16)f);
}
__device__ __forceinline__ float h2f(unsigned short u) {
  return (float)__builtin_bit_cast(_Float16, u);
}

// ---------------- QKV projection (f32-accurate via bf16 hi/lo 3-term MFMA) ----------------
// grid = NB * (NTOK/32), block = 256 (4 waves). Block: 32 tokens; wave w: out chans 16w..+15.
// Outputs: Qg,Kg = [b][n][64] fp16, Vg = [b][c][n] fp16.
__global__ __launch_bounds__(256) void qkv_proj(
    const float* __restrict__ x,
    const float* __restrict__ Wq, const float* __restrict__ bq,
    const float* __restrict__ Wk, const float* __restrict__ bk,
    const float* __restrict__ Wv, const float* __restrict__ bv,
    unsigned short* __restrict__ Qg, unsigned short* __restrict__ Kg,
    unsigned short* __restrict__ Vg)
{
  __shared__ __align__(16) float xs[64][38];   // [c][n]; stride 38 -> lg-read conflict 2-way
  const int tid = threadIdx.x;
  const int b  = blockIdx.x >> 7;
  const int n0 = (blockIdx.x & 127) << 5;
  const float* xb = x + (size_t)b * DIM * NTOK;

  for (int u = tid; u < 64 * 8; u += 256) {
    int c = u >> 3, q = u & 7;
    f32x4 v = *(const f32x4*)(xb + (size_t)c * NTOK + n0 + q * 4);
    *(f32x2*)&xs[c][q * 4]     = (f32x2){v[0], v[1]};
    *(f32x2*)&xs[c][q * 4 + 2] = (f32x2){v[2], v[3]};
  }
  __syncthreads();

  const int w = tid >> 6, l = tid & 63;
  const int lr = l & 15, lg = l >> 4;
  const int o0 = w << 4;

  // x^T hi/lo fragments: A-frag rows n (Q/K) == B-frag cols n (V). c = ks*32 + lg*8 + e.
  bf16x8 xh[2][2], xl[2][2];
  #pragma unroll
  for (int ns = 0; ns < 2; ns++) {
    #pragma unroll
    for (int ks = 0; ks < 2; ks++) {
      u16x8 uh, ul;
      #pragma unroll
      for (int e = 0; e < 8; e++) {
        float v = xs[ks * 32 + lg * 8 + e][ns * 16 + lr];
        __bf16 h = (__bf16)v;
        uh[e] = __builtin_bit_cast(unsigned short, h);
        ul[e] = __builtin_bit_cast(unsigned short, (__bf16)(v - (float)h));
      }
      xh[ns][ks] = __builtin_bit_cast(bf16x8, uh);
      xl[ns][ks] = __builtin_bit_cast(bf16x8, ul);
    }
  }

  // W hi/lo fragments: row o0+lr, 8 contiguous c. B-frag (W^T) for Q/K, A-frag for V.
  bf16x8 wh[3][2], wl[3][2];
  const float* Wm[3] = {Wq, Wk, Wv};
  #pragma unroll
  for (int m = 0; m < 3; m++) {
    #pragma unroll
    for (int ks = 0; ks < 2; ks++) {
      const float* p = Wm[m] + (o0 + lr) * DIM + ks * 32 + lg * 8;
      u16x8 uh, ul;
      #pragma unroll
      for (int e = 0; e < 8; e++) {
        float v = p[e];
        __bf16 h = (__bf16)v;
        uh[e] = __builtin_bit_cast(unsigned short, h);
        ul[e] = __builtin_bit_cast(unsigned short, (__bf16)(v - (float)h));
      }
      wh[m][ks] = __builtin_bit_cast(bf16x8, uh);
      wl[m][ks] = __builtin_bit_cast(bf16x8, ul);
    }
  }

  const float bqv = bq[o0 + lr], bkv = bk[o0 + lr];
  float bvv[4];
  #pragma unroll
  for (int r = 0; r < 4; r++) bvv[r] = bv[o0 + lg * 4 + r];

  #pragma unroll
  for (int ns = 0; ns < 2; ns++) {
    f32x4 aq = {bqv, bqv, bqv, bqv};
    f32x4 ak = {bkv, bkv, bkv, bkv};
    f32x4 av = {bvv[0], bvv[1], bvv[2], bvv[3]};
    #pragma unroll
    for (int ks = 0; ks < 2; ks++) {
      // (xh+xl)(wh+wl) ~= xh*wh + xh*wl + xl*wh  (dropped xl*wl ~ 2^-16 relative)
      aq = __builtin_amdgcn_mfma_f32_16x16x32_bf16(xh[ns][ks], wh[0][ks], aq, 0, 0, 0);
      aq = __builtin_amdgcn_mfma_f32_16x16x32_bf16(xh[ns][ks], wl[0][ks], aq, 0, 0, 0);
      aq = __builtin_amdgcn_mfma_f32_16x16x32_bf16(xl[ns][ks], wh[0][ks], aq, 0, 0, 0);
      ak = __builtin_amdgcn_mfma_f32_16x16x32_bf16(xh[ns][ks], wh[1][ks], ak, 0, 0, 0);
      ak = __builtin_amdgcn_mfma_f32_16x16x32_bf16(xh[ns][ks], wl[1][ks], ak, 0, 0, 0);
      ak = __builtin_amdgcn_mfma_f32_16x16x32_bf16(xl[ns][ks], wh[1][ks], ak, 0, 0, 0);
      av = __builtin_amdgcn_mfma_f32_16x16x32_bf16(wh[2][ks], xh[ns][ks], av, 0, 0, 0);
      av = __builtin_amdgcn_mfma_f32_16x16x32_bf16(wl[2][ks], xh[ns][ks], av, 0, 0, 0);
      av = __builtin_amdgcn_mfma_f32_16x16x32_bf16(wh[2][ks], xl[ns][ks], av, 0, 0, 0);
    }
    // Q/K tiles: D[row=n][col=o]; lane: o = o0+lr, n = n0+ns*16+4*lg+r
    #pragma unroll
    for (int r = 0; r < 4; r++) {
      int n = n0 + ns * 16 + lg * 4 + r;
      size_t base = ((size_t)b * NTOK + n) * DIM + o0 + lr;
      Qg[base] = f2h(aq[r]);
      Kg[base] = f2h(ak[r]);
    }
    // V tiles: D[row=o][col=n]; lane: n = n0+ns*16+lr, o = o0+4*lg+r
    #pragma unroll
    for (int r = 0; r < 4; r++) {
      int n = n0 + ns * 16 + lr;
      int o = o0 + lg * 4 + r;
      Vg[((size_t)b * DIM + o) * NTOK + n] = f2h(av[r]);
    }
  }
}

// ---------------- Flash attention, KV-split pass (register-prefetched) ----------------
// grid = NB*64*nsplit, block 256 (4 waves), wave w owns Q rows i0+16w..+15.
// K/V fragments read directly from global (L2-resident) into registers:
//   V[t] issued at tile start (hides under softmax), K[t+1] issued after QK^T.
__global__ __launch_bounds__(256, 4) void attn_part(
    const unsigned short* __restrict__ Qg, const unsigned short* __restrict__ Kg,
    const unsigned short* __restrict__ Vg,
    float* __restrict__ Op, float* __restrict__ Ml, float* __restrict__ out,
    int nsplit, int tiles, int direct)
{
  __shared__ __align__(16) unsigned short Pk[4 * 1056]; // per-wave P: [i_hi:4][j:66pad][i_lo:4]

  const int tid = threadIdx.x;
  const int w = tid >> 6, l = tid & 63;
  const int lr = l & 15, lg = l >> 4;
  const int s  = blockIdx.x % nsplit;
  const int bi = blockIdx.x / nsplit;
  const int b  = bi >> 6;
  const int i0 = (bi & 63) << 6;

  const unsigned short* Kb = Kg + (size_t)b * NTOK * DIM;   // [j][c]
  const unsigned short* Vb = Vg + (size_t)b * DIM * NTOK;   // [c][j]

  // Q fragments (registers, reused for all tiles)
  f16x8 qf[2];
  {
    const unsigned short* qp = Qg + ((size_t)b * NTOK + i0 + w * 16 + lr) * DIM;
    qf[0] = __builtin_bit_cast(f16x8, *(const u16x8*)(qp + lg * 8));
    qf[1] = __builtin_bit_cast(f16x8, *(const u16x8*)(qp + 32 + lg * 8));
  }

  float m[4], ls[4];
  f32x4 accO[4];
  #pragma unroll
  for (int r = 0; r < 4; r++) { m[r] = -3.0e38f; ls[r] = 0.f; }
  #pragma unroll
  for (int ct = 0; ct < 4; ct++) accO[ct] = (f32x4){0.f, 0.f, 0.f, 0.f};

  u16x8 kf[2][4];   // [ks][jt] K fragments for current tile (prefetched)
  u16x8 vf[2][4];   // [ks][ct] V fragments for current tile

  const int t0 = s * tiles;
  // prefetch K for first tile
  #pragma unroll
  for (int jt = 0; jt < 4; jt++)
    #pragma unroll
    for (int ks = 0; ks < 2; ks++)
      kf[ks][jt] = *(const u16x8*)(Kb + (size_t)(t0 * 64 + jt * 16 + lr) * DIM + ks * 32 + lg * 8);

  for (int t = 0; t < tiles; t++) {
    const int j0 = (t0 + t) << 6;

    // ---- issue V loads for this tile (consumed after softmax; latency hidden) ----
    #pragma unroll
    for (int ks = 0; ks < 2; ks++)
      #pragma unroll
      for (int ct = 0; ct < 4; ct++)
        vf[ks][ct] = *(const u16x8*)(Vb + (size_t)(ct * 16 + lr) * NTOK + j0 + ks * 32 + lg * 8);

    // ---- S = Q K^T from prefetched kf ----
    f32x4 S[4];
    __builtin_amdgcn_s_setprio(1);
    #pragma unroll
    for (int jt = 0; jt < 4; jt++) {
      f32x4 s4 = {0.f, 0.f, 0.f, 0.f};
      #pragma unroll
      for (int ks = 0; ks < 2; ks++)
        s4 = __builtin_amdgcn_mfma_f32_16x16x32_f16(qf[ks], __builtin_bit_cast(f16x8, kf[ks][jt]), s4, 0, 0, 0);
      S[jt] = s4;
    }
    __builtin_amdgcn_s_setprio(0);

    // ---- prefetch K for next tile (hidden under softmax + PV); clamp addr in-range ----
    const int jn = (t + 1 < tiles) ? (j0 + 64) : j0;
    #pragma unroll
    for (int jt = 0; jt < 4; jt++)
      #pragma unroll
      for (int ks = 0; ks < 2; ks++)
        kf[ks][jt] = *(const u16x8*)(Kb + (size_t)(jn + jt * 16 + lr) * DIM + ks * 32 + lg * 8);

    // ---- online softmax (rows i = 4*lg + r; reduce over j = lanes lr 0..15) ----
    float mx[4], mn[4], sc[4], rs[4];
    #pragma unroll
    for (int r = 0; r < 4; r++)
      mx[r] = fmaxf(fmaxf(S[0][r], S[1][r]), fmaxf(S[2][r], S[3][r]));
    #pragma unroll
    for (int sh = 8; sh >= 1; sh >>= 1) {
      #pragma unroll
      for (int r = 0; r < 4; r++)
        mx[r] = fmaxf(mx[r], __shfl_xor(mx[r], sh));
    }
    #pragma unroll
    for (int r = 0; r < 4; r++) {
      mn[r] = fmaxf(m[r], mx[r]);
      sc[r] = __expf(m[r] - mn[r]);
      rs[r] = 0.f;
    }
    #pragma unroll
    for (int jt = 0; jt < 4; jt++) {
      u16x4 pb;
      #pragma unroll
      for (int r = 0; r < 4; r++) {
        unsigned short u = f2h(__expf(S[jt][r] - mn[r]));
        pb[r] = u;
        rs[r] += h2f(u);     // sum rounded P for numerator/denominator consistency
      }
      *(u16x4*)&Pk[w * 1056 + lg * 264 + (jt * 16 + lr) * 4] = pb;
    }
    #pragma unroll
    for (int sh = 8; sh >= 1; sh >>= 1) {
      #pragma unroll
      for (int r = 0; r < 4; r++)
        rs[r] += __shfl_xor(rs[r], sh);
    }
    #pragma unroll
    for (int r = 0; r < 4; r++) {
      ls[r] = ls[r] * sc[r] + rs[r];
      m[r] = mn[r];
    }
    #pragma unroll
    for (int ct = 0; ct < 4; ct++) {
      #pragma unroll
      for (int r = 0; r < 4; r++)
        accO[ct][r] *= sc[r];
    }

    // ---- O += P V  (vf loads issued before QK^T; wait mostly satisfied) ----
    const int ihi = lr >> 2, ilo = lr & 3;
    #pragma unroll
    for (int ks = 0; ks < 2; ks++) {
      u16x8 pu;
      #pragma unroll
      for (int e = 0; e < 8; e++)
        pu[e] = Pk[w * 1056 + ihi * 264 + (ks * 32 + lg * 8 + e) * 4 + ilo];
      f16x8 pf = __builtin_bit_cast(f16x8, pu);
      __builtin_amdgcn_s_setprio(1);
      #pragma unroll
      for (int ct = 0; ct < 4; ct++)
        accO[ct] = __builtin_amdgcn_mfma_f32_16x16x32_f16(pf, __builtin_bit_cast(f16x8, vf[ks][ct]), accO[ct], 0, 0, 0);
      __builtin_amdgcn_s_setprio(0);
    }
    // no barrier: Pk is per-wave; K/V come from global
  }

  // lane holds cols c = ct*16+lr, rows i = w*16+lg*4+r (r contiguous in i)
  if (direct) {
    float rl[4];
    #pragma unroll
    for (int r = 0; r < 4; r++) rl[r] = 1.0f / ls[r];
    #pragma unroll
    for (int ct = 0; ct < 4; ct++) {
      f32x4 o;
      #pragma unroll
      for (int r = 0; r < 4; r++) o[r] = accO[ct][r] * rl[r];
      *(f32x4*)(out + ((size_t)b * DIM + ct * 16 + lr) * NTOK + i0 + w * 16 + lg * 4) = o;
    }
  } else {
    float* op = Op + (size_t)blockIdx.x * 4096;   // [c:64][i:64]
    #pragma unroll
    for (int ct = 0; ct < 4; ct++)
      *(f32x4*)(op + (ct * 16 + lr) * 64 + w * 16 + lg * 4) = accO[ct];
    if (lr == 0) {
      #pragma unroll
      for (int r = 0; r < 4; r++) {
        int i = w * 16 + lg * 4 + r;
        Ml[(size_t)blockIdx.x * 128 + i * 2]     = m[r];
        Ml[(size_t)blockIdx.x * 128 + i * 2 + 1] = ls[r];
      }
    }
  }
}

// ---------------- combine: merge nsplit partials per (b, i-block) ----------------
// grid = NB*64, block 256. out[b][c][i] = sum_s O_s[c][i]*exp(m_s-M) / sum_s l_s*exp(m_s-M)
__global__ __launch_bounds__(256) void attn_combine(
    const float* __restrict__ Op, const float* __restrict__ Ml,
    float* __restrict__ out, int nsplit)
{
  __shared__ float wls[64 * 8];    // [i][s] -> exp(m_s - M)/L (normalized weight)
  const int tid = threadIdx.x;
  const int b  = blockIdx.x >> 6;
  const int i0 = (blockIdx.x & 63) << 6;

  __shared__ float mlds[2][64 * 8];
  for (int u = tid; u < 64 * nsplit; u += 256) {
    int i = u / nsplit, s2 = u % nsplit;
    size_t base = ((size_t)blockIdx.x * nsplit + s2) * 128 + i * 2;
    mlds[0][i * 8 + s2] = Ml[base];
    mlds[1][i * 8 + s2] = Ml[base + 1];
  }
  __syncthreads();
  if (tid < 64) {
    float M = -3.0e38f;
    for (int s2 = 0; s2 < nsplit; s2++) M = fmaxf(M, mlds[0][tid * 8 + s2]);
    float L = 0.f;
    for (int s2 = 0; s2 < nsplit; s2++) L += mlds[1][tid * 8 + s2] * __expf(mlds[0][tid * 8 + s2] - M);
    float rL = 1.0f / L;
    for (int s2 = 0; s2 < nsplit; s2++) wls[tid * 8 + s2] = __expf(mlds[0][tid * 8 + s2] - M) * rL;
  }
  __syncthreads();

  for (int k4 = 0; k4 < 4; k4++) {
    int idx = k4 * 256 + tid;
    int c = idx >> 4, i = (idx & 15) * 4;
    f32x4 acc = {0.f, 0.f, 0.f, 0.f};
    for (int s2 = 0; s2 < nsplit; s2++) {
      f32x4 o = *(const f32x4*)(Op + ((size_t)blockIdx.x * nsplit + s2) * 4096 + c * 64 + i);
      #pragma unroll
      for (int r = 0; r < 4; r++)
        acc[r] += o[r] * wls[(i + r) * 8 + s2];
    }
    *(f32x4*)(out + ((size_t)b * DIM + c) * NTOK + i0 + i) = acc;
  }
}

extern "C" void kernel_launch(void* const* d_in, const int* in_sizes, int n_in,
                              void* d_out, int out_size, void* d_ws, size_t ws_size,
                              hipStream_t stream) {
  (void)in_sizes; (void)n_in; (void)out_size;
  const float* x  = (const float*)d_in[0];
  // d_in[1] = t  (unused by the reference computation)
  const float* Wq = (const float*)d_in[2];
  const float* bq = (const float*)d_in[3];
  const float* Wk = (const float*)d_in[4];
  const float* bk = (const float*)d_in[5];
  const float* Wv = (const float*)d_in[6];
  const float* bv = (const float*)d_in[7];
  float* out = (float*)d_out;

  unsigned short* Qg = (unsigned short*)d_ws;                 // [4][4096][64] fp16
  unsigned short* Kg = Qg + (size_t)NB * NTOK * DIM;          // [4][4096][64] fp16
  unsigned short* Vg = Kg + (size_t)NB * NTOK * DIM;          // [4][64][4096] fp16
  const size_t qkv_bytes = (size_t)3 * NB * NTOK * DIM * 2;   // 6.29 MB

  // nsplit=4 -> 1024 blocks (4/CU) matches residency; 16896 B of partials per block
  int nsplit = 1, direct = 1;
  if (qkv_bytes + (size_t)256 * 4 * 16896 <= ws_size)      { nsplit = 4; direct = 0; }
  else if (qkv_bytes + (size_t)256 * 2 * 16896 <= ws_size) { nsplit = 2; direct = 0; }
  float* Opf = (float*)((char*)d_ws + qkv_bytes);
  float* Mlf = Opf + (size_t)256 * nsplit * 4096;

  qkv_proj<<<NB * (NTOK / 32), 256, 0, stream>>>(x, Wq, bq, Wk, bk, Wv, bv, Qg, Kg, Vg);
  attn_part<<<NB * 64 * nsplit, 256, 0, stream>>>(Qg, Kg, Vg, Opf, Mlf, out,
                                                  nsplit, 64 / nsplit, direct);
  if (!direct)
    attn_combine<<<NB * 64, 256, 0, stream>>>(Opf, Mlf, out, nsplit);
}

// Round 10
// 156.716 us; speedup vs baseline: 1.4890x; 1.4890x over previous
//
#include <hip/hip_runtime.h>
#include <hip/hip_bf16.h>
#include <stdint.h>

// SelfAttention: B=4, C=64, H=W=64 -> N=4096, d=64.
// R8 design, compile-fixed: cvt_pkrtz returns __fp16x2 -> bit_cast to u32 directly.
// Swapped-operand attention (S^T = mfma(K,Q), O^T = mfma(V^T,P^T)) with fully
// in-register softmax (T12: cvt_pkrtz + permlane32_swap), deferred-max (T13, THR=10),
// no LDS / no barriers in attention. qkv: 1-wave blocks, 32x32 hi/lo bf16 MFMA.

#define DIM  64
#define NTOK 4096
#define NB   4

typedef float  f32x4  __attribute__((ext_vector_type(4)));
typedef float  f32x16 __attribute__((ext_vector_type(16)));
typedef __bf16 bf16x8 __attribute__((ext_vector_type(8)));
typedef _Float16 f16x8 __attribute__((ext_vector_type(8)));
typedef unsigned short u16x8 __attribute__((ext_vector_type(8)));
typedef unsigned int   u32x2 __attribute__((ext_vector_type(2)));
typedef unsigned int   u32x4 __attribute__((ext_vector_type(4)));

__device__ __forceinline__ unsigned short f2h(float f) {
  return __builtin_bit_cast(unsigned short, (_Float16)f);
}
__device__ __forceinline__ unsigned int fbits(float f) {
  return __builtin_bit_cast(unsigned int, f);
}
__device__ __forceinline__ float bitsf(unsigned int u) {
  return __builtin_bit_cast(float, u);
}
// pack two f32 -> two f16 (round-toward-zero), as raw u32
__device__ __forceinline__ unsigned int pkrtz(float a, float b) {
  return __builtin_bit_cast(unsigned int, __builtin_amdgcn_cvt_pkrtz(a, b));
}

// v_permlane32_swap_b32 semantics: (a,b) -> lane<32: {a_own, a_partner}; lane>=32:
// {b_partner, b_own}.  (partner = lane ^ 32)
__device__ __forceinline__ u32x2 pl32swap(unsigned int a, unsigned int b) {
#if __has_builtin(__builtin_amdgcn_permlane32_swap)
  auto t = __builtin_amdgcn_permlane32_swap((int)a, (int)b, false, false);
  return __builtin_bit_cast(u32x2, t);
#else
  unsigned int pa = (unsigned int)__shfl_xor((int)a, 32);
  unsigned int pb = (unsigned int)__shfl_xor((int)b, 32);
  int hi = (threadIdx.x & 63) >> 5;
  u32x2 r; r.x = hi ? pb : a; r.y = hi ? b : pa; return r;
#endif
}

// ---------------- QKV projection (f32-accurate via bf16 hi/lo, 32x32x16) ----------------
// 1-wave blocks (64 thr), grid = NB*128; wave handles 32 tokens, all 192 out-chans.
// Shared frags: xfrag serves Q/K (A) and V (B); wfrag serves Q/K (B) and V (A).
// Outputs: Qg,Kg = [b][n][64] fp16;  Vg = [b][c][n] fp16.
__global__ __launch_bounds__(64) void qkv_proj(
    const float* __restrict__ x,
    const float* __restrict__ Wq, const float* __restrict__ bq,
    const float* __restrict__ Wk, const float* __restrict__ bk,
    const float* __restrict__ Wv, const float* __restrict__ bv,
    unsigned short* __restrict__ Qg, unsigned short* __restrict__ Kg,
    unsigned short* __restrict__ Vg)
{
  const int l  = threadIdx.x & 63;
  const int hi = l >> 5, l5 = l & 31;
  const int b  = blockIdx.x >> 7;
  const int n0 = (blockIdx.x & 127) << 5;
  const float* xb = x + (size_t)b * DIM * NTOK;

  // x fragments: element(ks,e) = x[ks*16+hi*8+e][n0+l5]  (lane&31 = n, k = c)
  bf16x8 xh[4], xl[4];
  #pragma unroll
  for (int ks = 0; ks < 4; ks++) {
    u16x8 uh, ul;
    #pragma unroll
    for (int e = 0; e < 8; e++) {
      float v = xb[(size_t)(ks * 16 + hi * 8 + e) * NTOK + n0 + l5];
      __bf16 h = (__bf16)v;
      uh[e] = __builtin_bit_cast(unsigned short, h);
      ul[e] = __builtin_bit_cast(unsigned short, (__bf16)(v - (float)h));
    }
    xh[ks] = __builtin_bit_cast(bf16x8, uh);
    xl[ks] = __builtin_bit_cast(bf16x8, ul);
  }

  const float* Wm[3] = {Wq, Wk, Wv};
  const float* Bm[3] = {bq, bk, bv};

  #pragma unroll
  for (int mt = 0; mt < 3; mt++) {
    // W fragments: element(ct,ks,e) = W[ct*32+l5][ks*16+hi*8+e]  (lane&31 = o, k = c)
    bf16x8 wh[2][4], wl[2][4];
    #pragma unroll
    for (int ct = 0; ct < 2; ct++)
      #pragma unroll
      for (int ks = 0; ks < 4; ks++) {
        const float* p = Wm[mt] + (ct * 32 + l5) * DIM + ks * 16 + hi * 8;
        u16x8 uh, ul;
        #pragma unroll
        for (int e = 0; e < 8; e++) {
          float v = p[e];
          __bf16 h = (__bf16)v;
          uh[e] = __builtin_bit_cast(unsigned short, h);
          ul[e] = __builtin_bit_cast(unsigned short, (__bf16)(v - (float)h));
        }
        wh[ct][ks] = __builtin_bit_cast(bf16x8, uh);
        wl[ct][ks] = __builtin_bit_cast(bf16x8, ul);
      }

    if (mt < 2) {
      // Q/K: D[row=n][col=o] = mfma(A=x^T, B=W^T); bias depends on o = lane&31.
      unsigned short* dst = (mt == 0 ? Qg : Kg) + (size_t)b * NTOK * DIM;
      #pragma unroll
      for (int ct = 0; ct < 2; ct++) {
        float bias = Bm[mt][ct * 32 + l5];
        f32x16 acc;
        #pragma unroll
        for (int r = 0; r < 16; r++) acc[r] = bias;
        #pragma unroll
        for (int ks = 0; ks < 4; ks++) {
          acc = __builtin_amdgcn_mfma_f32_32x32x16_bf16(xh[ks], wh[ct][ks], acc, 0, 0, 0);
          acc = __builtin_amdgcn_mfma_f32_32x32x16_bf16(xh[ks], wl[ct][ks], acc, 0, 0, 0);
          acc = __builtin_amdgcn_mfma_f32_32x32x16_bf16(xl[ks], wh[ct][ks], acc, 0, 0, 0);
        }
        #pragma unroll
        for (int r = 0; r < 16; r++) {
          int n = n0 + (r & 3) + 8 * (r >> 2) + 4 * hi;
          dst[(size_t)n * DIM + ct * 32 + l5] = f2h(acc[r]);
        }
      }
    } else {
      // V: D[row=o][col=n] = mfma(A=W, B=x); bias depends on o = per-reg row.
      #pragma unroll
      for (int ct = 0; ct < 2; ct++) {
        f32x16 acc;
        #pragma unroll
        for (int r = 0; r < 16; r++) acc[r] = 0.f;
        #pragma unroll
        for (int ks = 0; ks < 4; ks++) {
          acc = __builtin_amdgcn_mfma_f32_32x32x16_bf16(wh[ct][ks], xh[ks], acc, 0, 0, 0);
          acc = __builtin_amdgcn_mfma_f32_32x32x16_bf16(wl[ct][ks], xh[ks], acc, 0, 0, 0);
          acc = __builtin_amdgcn_mfma_f32_32x32x16_bf16(wh[ct][ks], xl[ks], acc, 0, 0, 0);
        }
        #pragma unroll
        for (int r = 0; r < 16; r++) {
          int o = ct * 32 + (r & 3) + 8 * (r >> 2) + 4 * hi;
          Vg[((size_t)b * DIM + o) * NTOK + n0 + l5] = f2h(acc[r] + bv[o]);
        }
      }
    }
  }
}

// ---------------- Flash attention, swapped-operand, no LDS / no barriers ----------------
// Wave owns 32 Q-rows x one KV split segment. S^T = mfma(K,Q): lane&31 = i,
// regs = 16 j's; row stats 1 permlane. P -> f16 B-frag via cvt_pkrtz + 2 permlane.
// O^T = mfma(V^T, P^T): lane&31 = i -> rescale/normalize lane-local.
__global__ __launch_bounds__(256, 4) void attn_part(
    const unsigned short* __restrict__ Qg, const unsigned short* __restrict__ Kg,
    const unsigned short* __restrict__ Vg,
    float* __restrict__ Op, float* __restrict__ Ml, float* __restrict__ out,
    int nsplit, int tiles, int direct)
{
  const int tid = threadIdx.x;
  const int w = tid >> 6, l = tid & 63;
  const int hi = l >> 5, l5 = l & 31;
  int qtglob, s;
  if (direct) { qtglob = blockIdx.x * 4 + w; s = 0; }
  else { int spg = nsplit >> 2; qtglob = blockIdx.x / spg; s = (blockIdx.x - qtglob * spg) * 4 + w; }
  const int b  = qtglob >> 7;
  const int q0 = (qtglob & 127) << 5;

  const unsigned short* Kb = Kg + (size_t)b * NTOK * DIM;
  const unsigned short* Vb = Vg + (size_t)b * DIM * NTOK;

  // Q B-frag: lane&31 = i, k = ks*16 + hi*8 + e
  f16x8 qf[4];
  {
    const unsigned short* qp = Qg + ((size_t)b * NTOK + q0 + l5) * DIM + hi * 8;
    #pragma unroll
    for (int ks = 0; ks < 4; ks++)
      qf[ks] = __builtin_bit_cast(f16x8, *(const u16x8*)(qp + ks * 16));
  }

  float m = -3.0e38f, ls = 0.f;
  f32x16 acc0, acc1;
  #pragma unroll
  for (int r = 0; r < 16; r++) { acc0[r] = 0.f; acc1[r] = 0.f; }

  for (int t = 0; t < tiles; t++) {
    const int j0 = (s * tiles + t) << 5;

    // K A-frag: lane&31 = j, k = channel slice (16B contiguous)
    f16x8 kf[4];
    #pragma unroll
    for (int ks = 0; ks < 4; ks++)
      kf[ks] = __builtin_bit_cast(f16x8,
          *(const u16x8*)(Kb + (size_t)(j0 + l5) * DIM + ks * 16 + hi * 8));
    // V A-frag (for PV): lane&31 = c, k = j slice (16B contiguous); issue early (T14)
    f16x8 vf[2][2];
    #pragma unroll
    for (int js = 0; js < 2; js++)
      #pragma unroll
      for (int ct = 0; ct < 2; ct++)
        vf[js][ct] = __builtin_bit_cast(f16x8,
            *(const u16x8*)(Vb + (size_t)(ct * 32 + l5) * NTOK + j0 + js * 16 + hi * 8));

    // S^T[j][i]: lane holds col i = l5, rows j = (r&3)+8*(r>>2)+4*hi
    f32x16 st;
    #pragma unroll
    for (int r = 0; r < 16; r++) st[r] = 0.f;
    #pragma unroll
    for (int ks = 0; ks < 4; ks++)
      st = __builtin_amdgcn_mfma_f32_32x32x16_f16(kf[ks], qf[ks], st, 0, 0, 0);

    // full-row tile max: 15 local fmax + 1 permlane swap
    float tm = st[0];
    #pragma unroll
    for (int r = 1; r < 16; r++) tm = fmaxf(tm, st[r]);
    u32x2 sw = pl32swap(fbits(tm), fbits(tm));
    float tmf = fmaxf(bitsf(sw.x), bitsf(sw.y));

    // deferred max update (T13): keep P = exp(S-m) <= e^10 (f16-safe)
    if (__any(tmf > m + 10.0f)) {
      float mold = m;
      m = fmaxf(m, tmf);
      float sc = __expf(mold - m);
      ls *= sc;
      #pragma unroll
      for (int r = 0; r < 16; r++) { acc0[r] *= sc; acc1[r] *= sc; }
    }

    float p[16];
    #pragma unroll
    for (int r = 0; r < 16; r++) p[r] = __expf(st[r] - m);
    // tree-sum own 16 j's into partial row-sum
    {
      float s0 = p[0]+p[1], s1 = p[2]+p[3], s2 = p[4]+p[5], s3 = p[6]+p[7];
      float s4 = p[8]+p[9], s5 = p[10]+p[11], s6 = p[12]+p[13], s7 = p[14]+p[15];
      s0 += s1; s2 += s3; s4 += s5; s6 += s7; s0 += s2; s4 += s6;
      ls += s0 + s4;
    }

    // P^T B-frag assembly: word q of slice js must hold j-pair {16js+8hi+2q, +1}.
    // Held: p[r] <-> j = (r&3)+8*(r>>2)+4*hi.  Two permlane swaps per slice (T12).
    f16x8 pb[2];
    #pragma unroll
    for (int js = 0; js < 2; js++) {
      unsigned int w0 = pkrtz(p[8*js+0], p[8*js+1]);
      unsigned int w1 = pkrtz(p[8*js+2], p[8*js+3]);
      unsigned int w2 = pkrtz(p[8*js+4], p[8*js+5]);
      unsigned int w3 = pkrtz(p[8*js+6], p[8*js+7]);
      u32x2 r02 = pl32swap(w0, w2);
      u32x2 r13 = pl32swap(w1, w3);
      u32x4 pw = {r02.x, r13.x, r02.y, r13.y};
      pb[js] = __builtin_bit_cast(f16x8, pw);
    }

    // O^T[c][i] += V^T . P^T : same lane domain (col=i) as S^T and row stats
    acc0 = __builtin_amdgcn_mfma_f32_32x32x16_f16(vf[0][0], pb[0], acc0, 0, 0, 0);
    acc0 = __builtin_amdgcn_mfma_f32_32x32x16_f16(vf[1][0], pb[1], acc0, 0, 0, 0);
    acc1 = __builtin_amdgcn_mfma_f32_32x32x16_f16(vf[0][1], pb[0], acc1, 0, 0, 0);
    acc1 = __builtin_amdgcn_mfma_f32_32x32x16_f16(vf[1][1], pb[1], acc1, 0, 0, 0);
  }

  // combine hi-half partial sums: one permlane
  u32x2 lw = pl32swap(fbits(ls), fbits(ls));
  float lsf = bitsf(lw.x) + bitsf(lw.y);

  if (direct) {
    float inv = 1.0f / lsf;
    #pragma unroll
    for (int r = 0; r < 16; r++) {
      int row = (r & 3) + 8 * (r >> 2) + 4 * hi;
      out[((size_t)b * DIM + row) * NTOK + q0 + l5]        = acc0[r] * inv;
      out[((size_t)b * DIM + 32 + row) * NTOK + q0 + l5]   = acc1[r] * inv;
    }
  } else {
    const size_t widx = (size_t)qtglob * nsplit + s;
    float* op = Op + widx * 2048;           // [c:64][i:32]
    #pragma unroll
    for (int r = 0; r < 16; r++) {
      int row = (r & 3) + 8 * (r >> 2) + 4 * hi;
      op[row * 32 + l5]        = acc0[r];
      op[(32 + row) * 32 + l5] = acc1[r];
    }
    if (hi == 0) {
      Ml[widx * 64 + l5 * 2]     = m;
      Ml[widx * 64 + l5 * 2 + 1] = lsf;
    }
  }
}

// ---------------- combine: merge nsplit partials per (b, 32-row q-tile) ----------------
__global__ __launch_bounds__(256) void attn_combine(
    const float* __restrict__ Op, const float* __restrict__ Ml,
    float* __restrict__ out, int nsplit)
{
  __shared__ float wls[32][8];
  const int tid = threadIdx.x;
  const int qtglob = blockIdx.x;
  const int b  = qtglob >> 7;
  const int q0 = (qtglob & 127) << 5;

  if (tid < 32) {
    int i = tid;
    float M = -3.0e38f;
    for (int s = 0; s < nsplit; s++)
      M = fmaxf(M, Ml[((size_t)qtglob * nsplit + s) * 64 + i * 2]);
    float L = 0.f;
    for (int s = 0; s < nsplit; s++) {
      float ms = Ml[((size_t)qtglob * nsplit + s) * 64 + i * 2];
      float lsv = Ml[((size_t)qtglob * nsplit + s) * 64 + i * 2 + 1];
      L += lsv * __expf(ms - M);
    }
    float rL = 1.0f / L;
    for (int s = 0; s < nsplit; s++) {
      float ms = Ml[((size_t)qtglob * nsplit + s) * 64 + i * 2];
      wls[i][s] = __expf(ms - M) * rL;
    }
  }
  __syncthreads();

  const int c = tid >> 2, iq = (tid & 3) * 8;
  float acc[8];
  #pragma unroll
  for (int e = 0; e < 8; e++) acc[e] = 0.f;
  for (int s = 0; s < nsplit; s++) {
    const float* op = Op + ((size_t)qtglob * nsplit + s) * 2048 + c * 32 + iq;
    #pragma unroll
    for (int e = 0; e < 8; e++) acc[e] += op[e] * wls[iq + e][s];
  }
  float* o = out + ((size_t)b * DIM + c) * NTOK + q0 + iq;
  *(f32x4*)o       = (f32x4){acc[0], acc[1], acc[2], acc[3]};
  *(f32x4*)(o + 4) = (f32x4){acc[4], acc[5], acc[6], acc[7]};
}

extern "C" void kernel_launch(void* const* d_in, const int* in_sizes, int n_in,
                              void* d_out, int out_size, void* d_ws, size_t ws_size,
                              hipStream_t stream) {
  (void)in_sizes; (void)n_in; (void)out_size;
  const float* x  = (const float*)d_in[0];
  // d_in[1] = t (unused by the reference computation)
  const float* Wq = (const float*)d_in[2];
  const float* bq = (const float*)d_in[3];
  const float* Wk = (const float*)d_in[4];
  const float* bk = (const float*)d_in[5];
  const float* Wv = (const float*)d_in[6];
  const float* bv = (const float*)d_in[7];
  float* out = (float*)d_out;

  unsigned short* Qg = (unsigned short*)d_ws;                 // [4][4096][64] fp16
  unsigned short* Kg = Qg + (size_t)NB * NTOK * DIM;
  unsigned short* Vg = Kg + (size_t)NB * NTOK * DIM;          // [4][64][4096] fp16
  const size_t qkvB = (size_t)3 * NB * NTOK * DIM * 2;        // 6.29 MB

  // per split-wave partials: Op 2048 f32 + Ml 64 f32; 512 q-tiles total
  auto need = [&](int sp) {
    return qkvB + (size_t)512 * sp * 2048 * 4 + (size_t)512 * sp * 64 * 4;
  };
  int nsplit, direct;
  if (need(8) <= ws_size)      { nsplit = 8; direct = 0; }
  else if (need(4) <= ws_size) { nsplit = 4; direct = 0; }
  else                         { nsplit = 1; direct = 1; }
  const int tiles = 128 / nsplit;
  float* Opf = (float*)((char*)d_ws + qkvB);
  float* Mlf = Opf + (size_t)512 * nsplit * 2048;

  qkv_proj<<<NB * 128, 64, 0, stream>>>(x, Wq, bq, Wk, bk, Wv, bv, Qg, Kg, Vg);

  const int attn_grid = direct ? 128 : 512 * (nsplit / 4);
  attn_part<<<attn_grid, 256, 0, stream>>>(Qg, Kg, Vg, Opf, Mlf, out,
                                           nsplit, tiles, direct);
  if (!direct)
    attn_combine<<<NB * 128, 256, 0, stream>>>(Opf, Mlf, out, nsplit);
}

// Round 12
// 120.083 us; speedup vs baseline: 1.9432x; 1.3051x over previous
//
#include <hip/hip_runtime.h>
#include <hip/hip_bf16.h>
#include <stdint.h>

// SelfAttention: B=4, C=64, H=W=64 -> N=4096, d=64.
// R11 failed: w_prep slot encoding (16/matrix, bit3 dead) mismatched qkv_proj's
// reader (8/matrix) -> K used Wq-dups, V used Wk. R12: single fix - w_prep now
// writes the reader's exact layout (24 slots = mt*8+ct*4+ks). Attn unchanged
// (R5-verified LDS staging + R10-verified in-register swapped softmax).

#define DIM  64
#define NTOK 4096
#define NB   4

typedef float  f32x4  __attribute__((ext_vector_type(4)));
typedef float  f32x16 __attribute__((ext_vector_type(16)));
typedef __bf16 bf16x8 __attribute__((ext_vector_type(8)));
typedef _Float16 f16x8 __attribute__((ext_vector_type(8)));
typedef unsigned short u16x8 __attribute__((ext_vector_type(8)));
typedef unsigned int   u32x2 __attribute__((ext_vector_type(2)));
typedef unsigned int   u32x4 __attribute__((ext_vector_type(4)));

__device__ __forceinline__ void gload_lds16(const void* g, void* s) {
  __builtin_amdgcn_global_load_lds(
      (const __attribute__((address_space(1))) void*)g,
      (__attribute__((address_space(3))) void*)s, 16, 0, 0);
}
__device__ __forceinline__ unsigned short f2h(float f) {
  return __builtin_bit_cast(unsigned short, (_Float16)f);
}
__device__ __forceinline__ unsigned int fbits(float f) {
  return __builtin_bit_cast(unsigned int, f);
}
__device__ __forceinline__ float bitsf(unsigned int u) {
  return __builtin_bit_cast(float, u);
}
__device__ __forceinline__ unsigned int pkrtz(float a, float b) {
  return __builtin_bit_cast(unsigned int, __builtin_amdgcn_cvt_pkrtz(a, b));
}
// v_permlane32_swap_b32: (a,b) -> lane<32: {a_own, a_partner}; lane>=32: {b_partner, b_own}
__device__ __forceinline__ u32x2 pl32swap(unsigned int a, unsigned int b) {
#if __has_builtin(__builtin_amdgcn_permlane32_swap)
  auto t = __builtin_amdgcn_permlane32_swap((int)a, (int)b, false, false);
  return __builtin_bit_cast(u32x2, t);
#else
  unsigned int pa = (unsigned int)__shfl_xor((int)a, 32);
  unsigned int pb = (unsigned int)__shfl_xor((int)b, 32);
  int hi = (threadIdx.x & 63) >> 5;
  u32x2 r; r.x = hi ? pb : a; r.y = hi ? b : pa; return r;
#endif
}

// ---------------- w_prep: pack W hi/lo bf16 fragments in per-lane MFMA layout ----------
// slot = mt*8 + ct*4 + ks  (24 slots, EXACTLY the qkv_proj reader formula).
// entry = slot*64+lane; elem e = W[(ct*32+l5)*64 + ks*16 + hi*8 + e].
// grid = 6 blocks x 256 thr (1536 threads = 24 slots x 64 lanes).
__global__ __launch_bounds__(256) void w_prep(
    const float* __restrict__ Wq, const float* __restrict__ Wk, const float* __restrict__ Wv,
    unsigned short* __restrict__ Whg, unsigned short* __restrict__ Wlg)
{
  const int g = blockIdx.x * 256 + threadIdx.x;   // 0..1535
  const int slot = g >> 6, lane = g & 63;
  const int mt = slot >> 3, ct = (slot >> 2) & 1, ks = slot & 3;
  const int hi = lane >> 5, l5 = lane & 31;
  const float* W = (mt == 0) ? Wq : (mt == 1) ? Wk : Wv;
  const float* p = W + (ct * 32 + l5) * DIM + ks * 16 + hi * 8;
  u16x8 uh, ul;
  #pragma unroll
  for (int e = 0; e < 8; e++) {
    float v = p[e];
    __bf16 h = (__bf16)v;
    uh[e] = __builtin_bit_cast(unsigned short, h);
    ul[e] = __builtin_bit_cast(unsigned short, (__bf16)(v - (float)h));
  }
  *(u16x8*)&Whg[(size_t)g * 8] = uh;
  *(u16x8*)&Wlg[(size_t)g * 8] = ul;
}

// ---------------- QKV projection (f32-accurate via bf16 hi/lo, 32x32x16) ----------------
// grid = NB*3*128 one-wave blocks; block handles 32 tokens x ONE matrix (mt).
// Outputs: Qg,Kg = [b][n][64] fp16;  Vg = [b][c][n] fp16.
__global__ __launch_bounds__(64) void qkv_proj(
    const float* __restrict__ x,
    const float* __restrict__ bq, const float* __restrict__ bk, const float* __restrict__ bv,
    const unsigned short* __restrict__ Whg, const unsigned short* __restrict__ Wlg,
    unsigned short* __restrict__ Qg, unsigned short* __restrict__ Kg,
    unsigned short* __restrict__ Vg)
{
  const int l  = threadIdx.x & 63;
  const int hi = l >> 5, l5 = l & 31;
  const int b  = blockIdx.x / 384;
  const int r3 = blockIdx.x - b * 384;
  const int mt = r3 >> 7;
  const int n0 = (r3 & 127) << 5;
  const float* xb = x + (size_t)b * DIM * NTOK;

  // x frags: element(ks,e) = x[ks*16+hi*8+e][n0+l5]; coalesced 128B per (ks,e)
  bf16x8 xh[4], xl[4];
  #pragma unroll
  for (int ks = 0; ks < 4; ks++) {
    u16x8 uh, ul;
    #pragma unroll
    for (int e = 0; e < 8; e++) {
      float v = xb[(size_t)(ks * 16 + hi * 8 + e) * NTOK + n0 + l5];
      __bf16 h = (__bf16)v;
      uh[e] = __builtin_bit_cast(unsigned short, h);
      ul[e] = __builtin_bit_cast(unsigned short, (__bf16)(v - (float)h));
    }
    xh[ks] = __builtin_bit_cast(bf16x8, uh);
    xl[ks] = __builtin_bit_cast(bf16x8, ul);
  }

  // W frags: coalesced u16x8 loads from pre-packed layout (slot = mt*8+ct*4+ks)
  bf16x8 wh[2][4], wl[2][4];
  #pragma unroll
  for (int ct = 0; ct < 2; ct++)
    #pragma unroll
    for (int ks = 0; ks < 4; ks++) {
      size_t base = ((size_t)((mt * 2 + ct) * 4 + ks) * 64 + l) * 8;
      wh[ct][ks] = __builtin_bit_cast(bf16x8, *(const u16x8*)&Whg[base]);
      wl[ct][ks] = __builtin_bit_cast(bf16x8, *(const u16x8*)&Wlg[base]);
    }

  if (mt < 2) {
    // Q/K: D[row=n][col=o] = mfma(A=x^T, B=W^T); bias on o = ct*32+l5
    const float* bias_v = (mt == 0) ? bq : bk;
    unsigned short* dst = ((mt == 0) ? Qg : Kg) + (size_t)b * NTOK * DIM;
    #pragma unroll
    for (int ct = 0; ct < 2; ct++) {
      float bias = bias_v[ct * 32 + l5];
      f32x16 acc;
      #pragma unroll
      for (int r = 0; r < 16; r++) acc[r] = bias;
      #pragma unroll
      for (int ks = 0; ks < 4; ks++) {
        acc = __builtin_amdgcn_mfma_f32_32x32x16_bf16(xh[ks], wh[ct][ks], acc, 0, 0, 0);
        acc = __builtin_amdgcn_mfma_f32_32x32x16_bf16(xh[ks], wl[ct][ks], acc, 0, 0, 0);
        acc = __builtin_amdgcn_mfma_f32_32x32x16_bf16(xl[ks], wh[ct][ks], acc, 0, 0, 0);
      }
      #pragma unroll
      for (int r = 0; r < 16; r++) {
        int n = n0 + (r & 3) + 8 * (r >> 2) + 4 * hi;
        dst[(size_t)n * DIM + ct * 32 + l5] = f2h(acc[r]);
      }
    }
  } else {
    // V: D[row=o][col=n] = mfma(A=W, B=x)
    #pragma unroll
    for (int ct = 0; ct < 2; ct++) {
      f32x16 acc;
      #pragma unroll
      for (int r = 0; r < 16; r++) acc[r] = 0.f;
      #pragma unroll
      for (int ks = 0; ks < 4; ks++) {
        acc = __builtin_amdgcn_mfma_f32_32x32x16_bf16(wh[ct][ks], xh[ks], acc, 0, 0, 0);
        acc = __builtin_amdgcn_mfma_f32_32x32x16_bf16(wl[ct][ks], xh[ks], acc, 0, 0, 0);
        acc = __builtin_amdgcn_mfma_f32_32x32x16_bf16(wh[ct][ks], xl[ks], acc, 0, 0, 0);
      }
      #pragma unroll
      for (int r = 0; r < 16; r++) {
        int o = ct * 32 + (r & 3) + 8 * (r >> 2) + 4 * hi;
        Vg[((size_t)b * DIM + o) * NTOK + n0 + l5] = f2h(acc[r] + bv[o]);
      }
    }
  }
}

// ---------------- Flash attention: LDS-staged K/V + in-register softmax ----------------
// Block = 4 waves sharing (b, split) K/V tiles (KVBLK=64, double-buffered, swizzled).
// Wave w owns 32 q-rows. S^T = mfma(K,Q); O^T = mfma(V^T,P^T); softmax in registers.
__global__ __launch_bounds__(256) void attn_part(
    const unsigned short* __restrict__ Qg, const unsigned short* __restrict__ Kg,
    const unsigned short* __restrict__ Vg,
    float* __restrict__ Op, float* __restrict__ Ml, float* __restrict__ out,
    int nsplit, int tiles, int direct)
{
  __shared__ __align__(16) unsigned short Ks[2][64 * 64]; // [j][c] chunk-swizzled rows
  __shared__ __align__(16) unsigned short Vs[2][64 * 64]; // [c][j] chunk-swizzled rows

  const int tid = threadIdx.x;
  const int w = tid >> 6, l = tid & 63;
  const int hi = l >> 5, l5 = l & 31;
  int qtglob, s;
  if (direct) { qtglob = blockIdx.x * 4 + w; s = 0; }
  else {
    s = blockIdx.x % nsplit;
    int qg = (blockIdx.x / nsplit) & 31;
    int b_ = blockIdx.x / (nsplit * 32);
    qtglob = b_ * 128 + qg * 4 + w;
  }
  const int b  = qtglob >> 7;
  const int q0 = (qtglob & 127) << 5;

  const unsigned short* Kb = Kg + (size_t)b * NTOK * DIM;   // [j][c]
  const unsigned short* Vb = Vg + (size_t)b * DIM * NTOK;   // [c][j]

  // Q B-frag: lane&31 = i, k = ks*16 + hi*8 + e
  f16x8 qf[4];
  {
    const unsigned short* qp = Qg + ((size_t)b * NTOK + q0 + l5) * DIM + hi * 8;
    #pragma unroll
    for (int ks = 0; ks < 4; ks++)
      qf[ks] = __builtin_bit_cast(f16x8, *(const u16x8*)(qp + ks * 16));
  }

  float m = -3.0e38f, ls = 0.f;
  f32x16 acc0, acc1;
  #pragma unroll
  for (int r = 0; r < 16; r++) { acc0[r] = 0.f; acc1[r] = 0.f; }

  // stage one 64-j K/V tile (8KB each): 512 chunks of 16B; wave w moves chunks
  // (w*2+ss)*64+l; source pre-swizzled ps = p^(row&7) so linear LDS = swizzled layout.
  auto stage = [&](int t, int d) {
    const int j0 = (s * tiles + t) << 6;
    #pragma unroll
    for (int ss = 0; ss < 2; ss++) {
      int ch = (w * 2 + ss) * 64 + l;
      int row = ch >> 3, p = ch & 7;
      int ps = p ^ (row & 7);
      gload_lds16(Kb + (size_t)(j0 + row) * DIM + ps * 8, &Ks[d][(w * 2 + ss) * 512]);
      gload_lds16(Vb + (size_t)row * NTOK + j0 + ps * 8, &Vs[d][(w * 2 + ss) * 512]);
    }
  };

  stage(0, 0);
  __syncthreads();

  for (int t = 0; t < tiles; t++) {
    const int d = t & 1;
    if (t + 1 < tiles) stage(t + 1, d ^ 1);

    #pragma unroll
    for (int jb = 0; jb < 2; jb++) {
      // K A-frag from LDS: row = jb*32+l5, source chunk q=ks*2+hi at pos q^(row&7)
      const int krow = jb * 32 + l5;
      f16x8 kf[4];
      #pragma unroll
      for (int ks = 0; ks < 4; ks++) {
        int pos = (ks * 2 + hi) ^ (krow & 7);
        kf[ks] = __builtin_bit_cast(f16x8, *(const u16x8*)&Ks[d][krow * 64 + pos * 8]);
      }
      // V A-frag: row = ct*32+l5, chunk q = jb*4+js*2+hi at pos q^(row&7)
      f16x8 vf[2][2];
      #pragma unroll
      for (int js = 0; js < 2; js++)
        #pragma unroll
        for (int ct = 0; ct < 2; ct++) {
          int vrow = ct * 32 + l5;
          int pos = (jb * 4 + js * 2 + hi) ^ (vrow & 7);
          vf[js][ct] = __builtin_bit_cast(f16x8, *(const u16x8*)&Vs[d][vrow * 64 + pos * 8]);
        }

      // S^T[j][i]: lane holds col i = l5, rows j = jb*32 + (r&3)+8*(r>>2)+4*hi
      f32x16 st;
      #pragma unroll
      for (int r = 0; r < 16; r++) st[r] = 0.f;
      #pragma unroll
      for (int ks = 0; ks < 4; ks++)
        st = __builtin_amdgcn_mfma_f32_32x32x16_f16(kf[ks], qf[ks], st, 0, 0, 0);

      // tile max: 15 local fmax + 1 permlane swap
      float tm = st[0];
      #pragma unroll
      for (int r = 1; r < 16; r++) tm = fmaxf(tm, st[r]);
      u32x2 sw = pl32swap(fbits(tm), fbits(tm));
      float tmf = fmaxf(bitsf(sw.x), bitsf(sw.y));

      // deferred max update (T13): keep P = exp(S-m) <= e^10 (f16-safe)
      if (__any(tmf > m + 10.0f)) {
        float mold = m;
        m = fmaxf(m, tmf);
        float sc = __expf(mold - m);
        ls *= sc;
        #pragma unroll
        for (int r = 0; r < 16; r++) { acc0[r] *= sc; acc1[r] *= sc; }
      }

      float p[16];
      #pragma unroll
      for (int r = 0; r < 16; r++) p[r] = __expf(st[r] - m);
      {
        float s0 = p[0]+p[1], s1 = p[2]+p[3], s2 = p[4]+p[5], s3 = p[6]+p[7];
        float s4 = p[8]+p[9], s5 = p[10]+p[11], s6 = p[12]+p[13], s7 = p[14]+p[15];
        s0 += s1; s2 += s3; s4 += s5; s6 += s7; s0 += s2; s4 += s6;
        ls += s0 + s4;
      }

      // P^T B-frag via cvt_pkrtz + 2 permlane swaps per 16-j slice (T12)
      f16x8 pb[2];
      #pragma unroll
      for (int js = 0; js < 2; js++) {
        unsigned int w0 = pkrtz(p[8*js+0], p[8*js+1]);
        unsigned int w1 = pkrtz(p[8*js+2], p[8*js+3]);
        unsigned int w2 = pkrtz(p[8*js+4], p[8*js+5]);
        unsigned int w3 = pkrtz(p[8*js+6], p[8*js+7]);
        u32x2 r02 = pl32swap(w0, w2);
        u32x2 r13 = pl32swap(w1, w3);
        u32x4 pw = {r02.x, r13.x, r02.y, r13.y};
        pb[js] = __builtin_bit_cast(f16x8, pw);
      }

      // O^T[c][i] += V^T . P^T (same lane domain as row stats)
      acc0 = __builtin_amdgcn_mfma_f32_32x32x16_f16(vf[0][0], pb[0], acc0, 0, 0, 0);
      acc0 = __builtin_amdgcn_mfma_f32_32x32x16_f16(vf[1][0], pb[1], acc0, 0, 0, 0);
      acc1 = __builtin_amdgcn_mfma_f32_32x32x16_f16(vf[0][1], pb[0], acc1, 0, 0, 0);
      acc1 = __builtin_amdgcn_mfma_f32_32x32x16_f16(vf[1][1], pb[1], acc1, 0, 0, 0);
    }
    __syncthreads();   // staged t+1 complete (vmcnt drained) + buffer-reuse guard
  }

  u32x2 lw = pl32swap(fbits(ls), fbits(ls));
  float lsf = bitsf(lw.x) + bitsf(lw.y);

  if (direct) {
    float inv = 1.0f / lsf;
    #pragma unroll
    for (int r = 0; r < 16; r++) {
      int row = (r & 3) + 8 * (r >> 2) + 4 * hi;
      out[((size_t)b * DIM + row) * NTOK + q0 + l5]      = acc0[r] * inv;
      out[((size_t)b * DIM + 32 + row) * NTOK + q0 + l5] = acc1[r] * inv;
    }
  } else {
    const size_t widx = (size_t)qtglob * nsplit + s;
    float* op = Op + widx * 2048;           // [c:64][i:32]
    #pragma unroll
    for (int r = 0; r < 16; r++) {
      int row = (r & 3) + 8 * (r >> 2) + 4 * hi;
      op[row * 32 + l5]        = acc0[r];
      op[(32 + row) * 32 + l5] = acc1[r];
    }
    if (hi == 0) {
      Ml[widx * 64 + l5 * 2]     = m;
      Ml[widx * 64 + l5 * 2 + 1] = lsf;
    }
  }
}

// ---------------- combine: merge nsplit partials per (b, 32-row q-tile) ----------------
__global__ __launch_bounds__(256) void attn_combine(
    const float* __restrict__ Op, const float* __restrict__ Ml,
    float* __restrict__ out, int nsplit)
{
  __shared__ float wls[32][8];
  const int tid = threadIdx.x;
  const int qtglob = blockIdx.x;
  const int b  = qtglob >> 7;
  const int q0 = (qtglob & 127) << 5;

  if (tid < 32) {
    int i = tid;
    float M = -3.0e38f;
    for (int s = 0; s < nsplit; s++)
      M = fmaxf(M, Ml[((size_t)qtglob * nsplit + s) * 64 + i * 2]);
    float L = 0.f;
    for (int s = 0; s < nsplit; s++) {
      float ms = Ml[((size_t)qtglob * nsplit + s) * 64 + i * 2];
      float lsv = Ml[((size_t)qtglob * nsplit + s) * 64 + i * 2 + 1];
      L += lsv * __expf(ms - M);
    }
    float rL = 1.0f / L;
    for (int s = 0; s < nsplit; s++) {
      float ms = Ml[((size_t)qtglob * nsplit + s) * 64 + i * 2];
      wls[i][s] = __expf(ms - M) * rL;
    }
  }
  __syncthreads();

  const int c = tid >> 2, iq = (tid & 3) * 8;
  float acc[8];
  #pragma unroll
  for (int e = 0; e < 8; e++) acc[e] = 0.f;
  for (int s = 0; s < nsplit; s++) {
    const float* op = Op + ((size_t)qtglob * nsplit + s) * 2048 + c * 32 + iq;
    #pragma unroll
    for (int e = 0; e < 8; e++) acc[e] += op[e] * wls[iq + e][s];
  }
  float* o = out + ((size_t)b * DIM + c) * NTOK + q0 + iq;
  *(f32x4*)o       = (f32x4){acc[0], acc[1], acc[2], acc[3]};
  *(f32x4*)(o + 4) = (f32x4){acc[4], acc[5], acc[6], acc[7]};
}

extern "C" void kernel_launch(void* const* d_in, const int* in_sizes, int n_in,
                              void* d_out, int out_size, void* d_ws, size_t ws_size,
                              hipStream_t stream) {
  (void)in_sizes; (void)n_in; (void)out_size;
  const float* x  = (const float*)d_in[0];
  // d_in[1] = t (unused by the reference computation)
  const float* Wq = (const float*)d_in[2];
  const float* bq = (const float*)d_in[3];
  const float* Wk = (const float*)d_in[4];
  const float* bk = (const float*)d_in[5];
  const float* Wv = (const float*)d_in[6];
  const float* bv = (const float*)d_in[7];
  float* out = (float*)d_out;

  unsigned short* Qg = (unsigned short*)d_ws;                 // [4][4096][64] fp16
  unsigned short* Kg = Qg + (size_t)NB * NTOK * DIM;
  unsigned short* Vg = Kg + (size_t)NB * NTOK * DIM;          // [4][64][4096] fp16
  const size_t qkvB = (size_t)3 * NB * NTOK * DIM * 2;        // 6.29 MB
  unsigned short* Whg = (unsigned short*)((char*)d_ws + qkvB);   // 24 slots*64*8 u16
  unsigned short* Wlg = Whg + (size_t)24 * 64 * 8;
  const size_t wfB = qkvB + (size_t)2 * 24 * 64 * 8 * 2;      // + 24.6 KB

  auto need = [&](int sp) {
    return wfB + (size_t)512 * sp * 2048 * 4 + (size_t)512 * sp * 64 * 4;
  };
  int nsplit, direct;
  if (need(8) <= ws_size)      { nsplit = 8; direct = 0; }
  else if (need(4) <= ws_size) { nsplit = 4; direct = 0; }
  else                         { nsplit = 1; direct = 1; }
  const int tiles = 64 / nsplit;        // 64-j tiles per split
  float* Opf = (float*)((char*)d_ws + wfB);
  float* Mlf = Opf + (size_t)512 * nsplit * 2048;

  w_prep<<<6, 256, 0, stream>>>(Wq, Wk, Wv, Whg, Wlg);
  qkv_proj<<<NB * 384, 64, 0, stream>>>(x, bq, bk, bv, Whg, Wlg, Qg, Kg, Vg);

  const int attn_grid = direct ? 128 : 128 * nsplit;
  attn_part<<<attn_grid, 256, 0, stream>>>(Qg, Kg, Vg, Opf, Mlf, out,
                                           nsplit, tiles, direct);
  if (!direct)
    attn_combine<<<NB * 128, 256, 0, stream>>>(Opf, Mlf, out, nsplit);
}